// Round 1
// baseline (337.025 us; speedup 1.0000x reference)
//
#include <hip/hip_runtime.h>
#include <hip/hip_bf16.h>

typedef __attribute__((ext_vector_type(8))) short short8;
typedef __attribute__((ext_vector_type(4))) float f32x4;
typedef unsigned short u16;
typedef unsigned int u32;

#define NBATCH 8
#define NA 1000
#define MD 64
#define GD 50
#define FD 128
#define TOTAL (NBATCH * NA)  // 8000

__device__ __forceinline__ u16 f2bf(float f) {
    u32 x = __float_as_uint(f);
    return (u16)((x + 0x7fffu + ((x >> 16) & 1u)) >> 16);  // RNE
}
__device__ __forceinline__ float bf2f(u16 u) {
    return __uint_as_float(((u32)u) << 16);
}
__device__ __forceinline__ u32 pkbf(float x, float y) {
    // packed fp32->bf16 RNE (v_cvt_pk_bf16_f32 on gfx950)
    __hip_bfloat162 h = __float22bfloat162_rn(float2{x, y});
    return *reinterpret_cast<u32*>(&h);
}
__device__ __forceinline__ float tanh_fast(float x) {
    float e = __expf(2.0f * x);
    return 1.0f - 2.0f * __builtin_amdgcn_rcpf(e + 1.0f);
}
__device__ __forceinline__ f32x4 mfma16(short8 a, short8 b, f32x4 c) {
    return __builtin_amdgcn_mfma_f32_16x16x32_bf16(a, b, c, 0, 0, 0);
}

// ---------------- k0: fp32 weights -> bf16 transposed/padded panels (40 blocks) ----------------
// W1T: [128 n][72 k], k<50 valid else 0.
// W2T/WiT/Wo1T/Wo2T: [2 p][128 n][72 kk], k=p*64+kk, kk<64 valid else 0.
__global__ void k0_prep(const float* __restrict__ W1, const float* __restrict__ W2,
                        const float* __restrict__ Wi, const float* __restrict__ Wo1,
                        const float* __restrict__ Wo2,
                        u16* __restrict__ W1T, u16* __restrict__ W2T,
                        u16* __restrict__ WiT, u16* __restrict__ Wo1T,
                        u16* __restrict__ Wo2T) {
    const int g0 = blockIdx.x * 256 + threadIdx.x;
    const int gstep = gridDim.x * 256;
    for (int i = g0; i < 128 * 72; i += gstep) {
        int n = i / 72, k = i - n * 72;
        int ks = (k < GD) ? k : 0;
        W1T[i] = (k < GD) ? f2bf(W1[ks * FD + n]) : (u16)0;
    }
    for (int i = g0; i < 2 * 128 * 72; i += gstep) {
        int p = i / 9216;
        int rem = i - p * 9216;
        int n = rem / 72, kk = rem - n * 72;
        bool valid = kk < 64;
        int k = p * 64 + (valid ? kk : 0);  // clamped, in-bounds
        W2T[i]  = valid ? f2bf(W2[k * FD + n])  : (u16)0;
        WiT[i]  = valid ? f2bf(Wi[k * FD + n])  : (u16)0;
        Wo1T[i] = valid ? f2bf(Wo1[k * FD + n]) : (u16)0;
        Wo2T[i] = valid ? f2bf(Wo2[k * FD + n]) : (u16)0;
    }
}

// ---------------- k1: init = features @ W_init -> bf16 in ws ----------------
// 64 rows/block, 125 blocks (8000 exact). LDS 35840 -> 4 blocks/CU.
__global__ __launch_bounds__(256, 4) void k1_init(const float* __restrict__ feat,
                                                  const u16* __restrict__ WiT,
                                                  u16* __restrict__ initB) {
    __shared__ alignas(16) char smem[35840];
    u16* sA = (u16*)smem;              // [64][136] bf16
    u16* sW = (u16*)(smem + 17408);    // [128][72] panel
    const int tid = threadIdx.x, wid = tid >> 6, lane = tid & 63;
    const int quad = lane >> 4, col = lane & 15, rw = wid * 16;
    const int row0 = blockIdx.x * 64;

    for (int i = tid; i < 2048; i += 256) {
        int r = i >> 5, c = (i & 31) * 4;
        float4 v = *(const float4*)&feat[(size_t)(row0 + r) * FD + c];
        u32* p = (u32*)&sA[r * 136 + c];
        p[0] = pkbf(v.x, v.y);
        p[1] = pkbf(v.z, v.w);
    }
    for (int i = tid; i < 1152; i += 256) ((int4*)sW)[i] = ((const int4*)WiT)[i];
    __syncthreads();

    f32x4 acc[8];
    const f32x4 zf = {0.f, 0.f, 0.f, 0.f};
#pragma unroll
    for (int nt = 0; nt < 8; ++nt) acc[nt] = zf;

    for (int half = 0; half < 2; ++half) {
        if (half) {
            __syncthreads();
            for (int i = tid; i < 1152; i += 256)
                ((int4*)sW)[i] = ((const int4*)(WiT + 9216))[i];
            __syncthreads();
        }
#pragma unroll
        for (int ks = 0; ks < 2; ++ks) {
            const int ka = half * 64 + ks * 32 + quad * 8;
            const int kb = ks * 32 + quad * 8;
            short8 a0 = *(const short8*)&sA[(rw + col) * 136 + ka];
#pragma unroll
            for (int nt = 0; nt < 8; ++nt) {
                short8 bfr = *(const short8*)&sW[(nt * 16 + col) * 72 + kb];
                acc[nt] = mfma16(a0, bfr, acc[nt]);
            }
        }
    }
#pragma unroll
    for (int nt = 0; nt < 8; ++nt)
#pragma unroll
        for (int r = 0; r < 4; ++r) {
            int gr = row0 + rw + quad * 4 + r;
            initB[(size_t)gr * FD + nt * 16 + col] = f2bf(acc[nt][r]);
        }
}

// ---------------- k2: fused CFConv + attention, 2 atoms / block ----------------
// LDS 53,248 B -> 3 blocks/CU (12 waves, 3/SIMD -> VGPR budget 170).
// Gather of neighbor init rows is ISSUED IN PHASE 0 (raw u16 in regs),
// completes at the first barrier drain, consumed in the epilogue.
__global__ __launch_bounds__(256, 3) void k2_main(
    const float* __restrict__ rbf, const int* __restrict__ nl,
    const u16* __restrict__ initB,
    const u16* __restrict__ W1T, const u16* __restrict__ W2T,
    const float* __restrict__ b1, const float* __restrict__ b2,
    const float* __restrict__ nbrw,
    float* __restrict__ aggOut, float* __restrict__ attnO) {
    __shared__ alignas(16) char smem[53248];
    u16* sA = (u16*)smem;              // rbf [128][72] -> H [128][136]
    u16* sB = (u16*)(smem + 34816);    // W1 -> W2 panel0 -> W2 panel1, [128][72]
    // epilogue aux aliases sA (H dead by then):
    float* logitS = (float*)smem;            // [128]    bytes 0..511
    float* aggS   = (float*)(smem + 1024);   // [4][128] bytes 1024..3071

    const int tid = threadIdx.x, wid = tid >> 6, lane = tid & 63;
    const int quad = lane >> 4, col = lane & 15, rw = wid * 32;
    const int blk = blockIdx.x;
    const int b = blk / 500;
    const int n0 = (blk - b * 500) * 2;
    const int atom0 = b * NA + n0;
    const size_t rbf_base = (size_t)atom0 * (MD * GD);

    // ---- phase 0: neighbor indices (per-thread, broadcast within quad) ----
    int nlv[2][4];
#pragma unroll
    for (int mt = 0; mt < 2; ++mt)
#pragma unroll
        for (int r = 0; r < 4; ++r)
            nlv[mt][r] = nl[atom0 * MD + rw + mt * 16 + quad * 4 + r];

    // zero pad cols [50,64) of rbf tile (K padded to 64)
    for (int i = tid; i < 128 * 14; i += 256) {
        int r = i / 14;
        sA[r * 72 + 50 + (i - r * 14)] = 0;
    }
    // rbf fp32 -> bf16 packed pairs (50 even: pairs never straddle rows)
    for (int i = tid; i < 3200; i += 256) {
        int e = 2 * i;
        int r = e / 50, g = e - r * 50;
        float2 v = *(const float2*)&rbf[rbf_base + e];
        *(u32*)&sA[r * 72 + g] = pkbf(v.x, v.y);
    }
    for (int i = tid; i < 1152; i += 256) ((int4*)sB)[i] = ((const int4*)W1T)[i];

    // ---- issue gather NOW: 64 u16 loads/thread, hidden under layer1/layer2 ----
    u32 graw[2][8][4];
#pragma unroll
    for (int mt = 0; mt < 2; ++mt)
#pragma unroll
        for (int r = 0; r < 4; ++r) {
            int ro = (b * NA + nlv[mt][r]) * FD + col;
#pragma unroll
            for (int nt = 0; nt < 8; ++nt)
                graw[mt][nt][r] = initB[ro + nt * 16];
        }
    __syncthreads();

    // ---- layer 1: rbf @ W1 ----
    f32x4 acc[2][8];
    const f32x4 zf = {0.f, 0.f, 0.f, 0.f};
#pragma unroll
    for (int mt = 0; mt < 2; ++mt)
#pragma unroll
        for (int nt = 0; nt < 8; ++nt) acc[mt][nt] = zf;
#pragma unroll
    for (int ks = 0; ks < 2; ++ks) {
        const int ka = ks * 32 + quad * 8;
        short8 a0 = *(const short8*)&sA[(rw + col) * 72 + ka];
        short8 a1 = *(const short8*)&sA[(rw + 16 + col) * 72 + ka];
#pragma unroll
        for (int nt = 0; nt < 8; ++nt) {
            short8 bfr = *(const short8*)&sB[(nt * 16 + col) * 72 + ka];
            acc[0][nt] = mfma16(a0, bfr, acc[0][nt]);
            acc[1][nt] = mfma16(a1, bfr, acc[1][nt]);
        }
    }
    __syncthreads();  // rbf/W1 reads complete before overwrite

    // H = tanh(.+b1) -> sA [128][136]; stage W2 panel 0 into sB
    float bias[8];
#pragma unroll
    for (int nt = 0; nt < 8; ++nt) bias[nt] = b1[nt * 16 + col];
#pragma unroll
    for (int mt = 0; mt < 2; ++mt)
#pragma unroll
        for (int nt = 0; nt < 8; ++nt)
#pragma unroll
            for (int r = 0; r < 4; ++r) {
                int row = rw + mt * 16 + quad * 4 + r;
                sA[row * 136 + nt * 16 + col] =
                    f2bf(tanh_fast(acc[mt][nt][r] + bias[nt]));
            }
    for (int i = tid; i < 1152; i += 256) ((int4*)sB)[i] = ((const int4*)W2T)[i];
    __syncthreads();

    // ---- layer 2: H @ W2, two 64-K panels ----
    f32x4 acc2[2][8];
#pragma unroll
    for (int mt = 0; mt < 2; ++mt)
#pragma unroll
        for (int nt = 0; nt < 8; ++nt) acc2[mt][nt] = zf;
    for (int half = 0; half < 2; ++half) {
        if (half) {
            __syncthreads();
            for (int i = tid; i < 1152; i += 256)
                ((int4*)sB)[i] = ((const int4*)(W2T + 9216))[i];
            __syncthreads();
        }
#pragma unroll
        for (int ks = 0; ks < 2; ++ks) {
            const int ka = half * 64 + ks * 32 + quad * 8;
            const int kb = ks * 32 + quad * 8;
            short8 a0 = *(const short8*)&sA[(rw + col) * 136 + ka];
            short8 a1 = *(const short8*)&sA[(rw + 16 + col) * 136 + ka];
#pragma unroll
            for (int nt = 0; nt < 8; ++nt) {
                short8 bfr = *(const short8*)&sB[(nt * 16 + col) * 72 + kb];
                acc2[0][nt] = mfma16(a0, bfr, acc2[0][nt]);
                acc2[1][nt] = mfma16(a1, bfr, acc2[1][nt]);
            }
        }
    }

    // ---- epilogue: conv (gather already in regs), logits, softmax, agg ----
    float wv[8];
#pragma unroll
    for (int nt = 0; nt < 8; ++nt) {
        bias[nt] = b2[nt * 16 + col];
        wv[nt] = nbrw[nt * 16 + col];
    }
    float part[2][4] = {{0.f, 0.f, 0.f, 0.f}, {0.f, 0.f, 0.f, 0.f}};
#pragma unroll
    for (int mt = 0; mt < 2; ++mt)
#pragma unroll
        for (int nt = 0; nt < 8; ++nt)
#pragma unroll
            for (int r = 0; r < 4; ++r) {
                float nb = bf2f((u16)graw[mt][nt][r]);
                float cv = nb * (acc2[mt][nt][r] + bias[nt]);
                acc2[mt][nt][r] = cv;  // conv stays in regs (fp32)
                part[mt][r] += cv * wv[nt];
            }
#pragma unroll
    for (int d = 1; d < 16; d <<= 1)
#pragma unroll
        for (int mt = 0; mt < 2; ++mt)
#pragma unroll
            for (int r = 0; r < 4; ++r)
                part[mt][r] += __shfl_xor(part[mt][r], d, 64);
    __syncthreads();  // all layer-2 LDS reads done before aux aliases sA
    if (col == 0) {
#pragma unroll
        for (int mt = 0; mt < 2; ++mt)
#pragma unroll
            for (int r = 0; r < 4; ++r)
                logitS[rw + mt * 16 + quad * 4 + r] = part[mt][r];
    }
    __syncthreads();

    // all-wave redundant softmax: each wave owns its atom's 64 logits
    float attw[2][4];
    {
        const int base = rw & 64;  // waves 0,1 -> atom0 ; waves 2,3 -> atom1
        float x = logitS[base + lane];
        float m = x;
#pragma unroll
        for (int d = 1; d < 64; d <<= 1) m = fmaxf(m, __shfl_xor(m, d, 64));
        float e = __expf(x - m);
        float s = e;
#pragma unroll
        for (int d = 1; d < 64; d <<= 1) s += __shfl_xor(s, d, 64);
        float a = e / s;
        if ((wid & 1) == 0)
            attnO[(size_t)(atom0 + (wid >> 1)) * MD + lane] = a;
        // redistribute to row owners: row R's attn sits at lane R-base
#pragma unroll
        for (int mt = 0; mt < 2; ++mt)
#pragma unroll
            for (int r = 0; r < 4; ++r)
                attw[mt][r] = __shfl(a, (rw & 32) + mt * 16 + quad * 4 + r, 64);
    }

    float aggp[8] = {0.f, 0.f, 0.f, 0.f, 0.f, 0.f, 0.f, 0.f};
#pragma unroll
    for (int mt = 0; mt < 2; ++mt)
#pragma unroll
        for (int r = 0; r < 4; ++r) {
            float a = attw[mt][r];
#pragma unroll
            for (int nt = 0; nt < 8; ++nt) aggp[nt] += a * acc2[mt][nt][r];
        }
#pragma unroll
    for (int d = 16; d < 64; d <<= 1)
#pragma unroll
        for (int nt = 0; nt < 8; ++nt) aggp[nt] += __shfl_xor(aggp[nt], d, 64);
    if (quad == 0) {
#pragma unroll
        for (int nt = 0; nt < 8; ++nt) aggS[wid * 128 + nt * 16 + col] = aggp[nt];
    }
    __syncthreads();
    {
        int a = tid >> 7;   // which atom
        int c = tid & 127;  // feature
        float v = aggS[(2 * a) * 128 + c] + aggS[(2 * a + 1) * 128 + c];
        aggOut[(size_t)(atom0 + a) * FD + c] = v;  // agg scratch in d_out rows
    }
}

// ---------------- k3: out = tanh(agg@Wo1+bo1)@Wo2+bo2, IN PLACE on d_out rows ----------------
// 64 rows/block, 125 blocks. LDS 35840 -> 4 blocks/CU.
__global__ __launch_bounds__(256, 4) void k3_out(
    float* __restrict__ outp, const u16* __restrict__ Wo1T,
    const u16* __restrict__ Wo2T, const float* __restrict__ bo1,
    const float* __restrict__ bo2) {
    __shared__ alignas(16) char smem[35840];
    u16* sA = (u16*)smem;            // [64][136]: agg rows, then t1
    u16* sW = (u16*)(smem + 17408);  // [128][72] panel
    const int tid = threadIdx.x, wid = tid >> 6, lane = tid & 63;
    const int quad = lane >> 4, col = lane & 15, rw = wid * 16;
    const int row0 = blockIdx.x * 64;

    // stage agg (fp32, from d_out) -> bf16 LDS; ALL reads before first barrier
    for (int i = tid; i < 2048; i += 256) {
        int r = i >> 5, c = (i & 31) * 4;
        float4 v = *(const float4*)&outp[(size_t)(row0 + r) * FD + c];
        u32* p = (u32*)&sA[r * 136 + c];
        p[0] = pkbf(v.x, v.y);
        p[1] = pkbf(v.z, v.w);
    }
    for (int i = tid; i < 1152; i += 256) ((int4*)sW)[i] = ((const int4*)Wo1T)[i];
    __syncthreads();

    f32x4 acc[8];
    const f32x4 zf = {0.f, 0.f, 0.f, 0.f};
#pragma unroll
    for (int nt = 0; nt < 8; ++nt) acc[nt] = zf;
    for (int half = 0; half < 2; ++half) {
        if (half) {
            __syncthreads();
            for (int i = tid; i < 1152; i += 256)
                ((int4*)sW)[i] = ((const int4*)(Wo1T + 9216))[i];
            __syncthreads();
        }
#pragma unroll
        for (int ks = 0; ks < 2; ++ks) {
            const int ka = half * 64 + ks * 32 + quad * 8;
            const int kb = ks * 32 + quad * 8;
            short8 a0 = *(const short8*)&sA[(rw + col) * 136 + ka];
#pragma unroll
            for (int nt = 0; nt < 8; ++nt) {
                short8 bfr = *(const short8*)&sW[(nt * 16 + col) * 72 + kb];
                acc[nt] = mfma16(a0, bfr, acc[nt]);
            }
        }
    }
    __syncthreads();  // layer-1 reads done before t1/sW overwrite

    float bias[8];
#pragma unroll
    for (int nt = 0; nt < 8; ++nt) bias[nt] = bo1[nt * 16 + col];
#pragma unroll
    for (int nt = 0; nt < 8; ++nt)
#pragma unroll
        for (int r = 0; r < 4; ++r) {
            int row = rw + quad * 4 + r;
            sA[row * 136 + nt * 16 + col] = f2bf(tanh_fast(acc[nt][r] + bias[nt]));
        }
    for (int i = tid; i < 1152; i += 256) ((int4*)sW)[i] = ((const int4*)Wo2T)[i];
    __syncthreads();

    f32x4 acc2[8];
#pragma unroll
    for (int nt = 0; nt < 8; ++nt) acc2[nt] = zf;
    for (int half = 0; half < 2; ++half) {
        if (half) {
            __syncthreads();
            for (int i = tid; i < 1152; i += 256)
                ((int4*)sW)[i] = ((const int4*)(Wo2T + 9216))[i];
            __syncthreads();
        }
#pragma unroll
        for (int ks = 0; ks < 2; ++ks) {
            const int ka = half * 64 + ks * 32 + quad * 8;
            const int kb = ks * 32 + quad * 8;
            short8 a0 = *(const short8*)&sA[(rw + col) * 136 + ka];
#pragma unroll
            for (int nt = 0; nt < 8; ++nt) {
                short8 bfr = *(const short8*)&sW[(nt * 16 + col) * 72 + kb];
                acc2[nt] = mfma16(a0, bfr, acc2[nt]);
            }
        }
    }
#pragma unroll
    for (int nt = 0; nt < 8; ++nt) bias[nt] = bo2[nt * 16 + col];
#pragma unroll
    for (int nt = 0; nt < 8; ++nt)
#pragma unroll
        for (int r = 0; r < 4; ++r) {
            int gr = row0 + rw + quad * 4 + r;
            outp[(size_t)gr * FD + nt * 16 + col] = acc2[nt][r] + bias[nt];
        }
}

extern "C" void kernel_launch(void* const* d_in, const int* in_sizes, int n_in,
                              void* d_out, int out_size, void* d_ws,
                              size_t ws_size, hipStream_t stream) {
    const float* feat = (const float*)d_in[0];
    const float* rbf  = (const float*)d_in[1];
    const int*   nl   = (const int*)d_in[2];
    const float* Wi   = (const float*)d_in[3];
    const float* W1   = (const float*)d_in[4];
    const float* b1   = (const float*)d_in[5];
    const float* W2   = (const float*)d_in[6];
    const float* b2   = (const float*)d_in[7];
    const float* nbrw = (const float*)d_in[8];
    const float* Wo1  = (const float*)d_in[9];
    const float* bo1  = (const float*)d_in[10];
    const float* Wo2  = (const float*)d_in[11];
    const float* bo2  = (const float*)d_in[12];

    float* outp  = (float*)d_out;               // [8000][128] (agg scratch, then final)
    float* attnp = outp + (size_t)TOTAL * FD;   // [8000][64]

    char* ws = (char*)d_ws;                     // total use: 2,213,888 B
    u16* initB = (u16*)ws;                      // 2,048,000 B
    u16* W1T   = (u16*)(ws + 2048000);          // 18,432 B
    u16* W2T   = (u16*)(ws + 2048000 + 18432);  // 36,864 B
    u16* WiT   = (u16*)(ws + 2048000 + 18432 + 36864);
    u16* Wo1T  = (u16*)(ws + 2048000 + 18432 + 2 * 36864);
    u16* Wo2T  = (u16*)(ws + 2048000 + 18432 + 3 * 36864);

    hipLaunchKernelGGL(k0_prep, dim3(40), dim3(256), 0, stream,
                       W1, W2, Wi, Wo1, Wo2, W1T, W2T, WiT, Wo1T, Wo2T);
    hipLaunchKernelGGL(k1_init, dim3(125), dim3(256), 0, stream, feat, WiT, initB);
    hipLaunchKernelGGL(k2_main, dim3(4000), dim3(256), 0, stream,
                       rbf, nl, initB, W1T, W2T, b1, b2, nbrw, outp, attnp);
    hipLaunchKernelGGL(k3_out, dim3(125), dim3(256), 0, stream,
                       outp, Wo1T, Wo2T, bo1, bo2);
}

// Round 3
// 261.244 us; speedup vs baseline: 1.2901x; 1.2901x over previous
//
#include <hip/hip_runtime.h>
#include <hip/hip_bf16.h>

typedef __attribute__((ext_vector_type(8))) short short8;
typedef __attribute__((ext_vector_type(4))) float f32x4;
typedef unsigned short u16;
typedef unsigned int u32;

#define NBATCH 8
#define NA 1000
#define MD 64
#define GD 50
#define FD 128
#define TOTAL (NBATCH * NA)  // 8000

__device__ __forceinline__ u16 f2bf(float f) {
    u32 x = __float_as_uint(f);
    return (u16)((x + 0x7fffu + ((x >> 16) & 1u)) >> 16);  // RNE
}
__device__ __forceinline__ float bf2f(u16 u) {
    return __uint_as_float(((u32)u) << 16);
}
__device__ __forceinline__ u32 pkbf(float x, float y) {
    __hip_bfloat162 h = __float22bfloat162_rn(float2{x, y});
    return *reinterpret_cast<u32*>(&h);
}
__device__ __forceinline__ float tanh_fast(float x) {
    float e = __expf(2.0f * x);
    return 1.0f - 2.0f * __builtin_amdgcn_rcpf(e + 1.0f);
}
__device__ __forceinline__ f32x4 mfma16(short8 a, short8 b, f32x4 c) {
    return __builtin_amdgcn_mfma_f32_16x16x32_bf16(a, b, c, 0, 0, 0);
}

// ---------------- k0: pack fp32 weights into MFMA B-fragment order ----------------
// For K=128 mats: seg = (half*2+ks)*8+nt (32 segs); P[seg*512 + lane*8 + j] =
//   bf16(W[k*FD+n]) with k = half*64+ks*32+(lane>>4)*8+j, n = nt*16+(lane&15).
// A wave's B-frag load for (half,ks,nt) is then ONE coalesced 1KB dwordx4.
// W1P (K=50 padded to 64): seg = ks*8+nt (16 segs), k>=50 -> 0.
__global__ void k0_prep(const float* __restrict__ W1, const float* __restrict__ W2,
                        const float* __restrict__ Wi, const float* __restrict__ Wo1,
                        const float* __restrict__ Wo2,
                        u16* __restrict__ W1P, u16* __restrict__ W2P,
                        u16* __restrict__ WiP, u16* __restrict__ Wo1P,
                        u16* __restrict__ Wo2P) {
    const int g0 = blockIdx.x * 256 + threadIdx.x;
    const int gstep = gridDim.x * 256;
    for (int p = g0; p < 16 * 512; p += gstep) {
        int seg = p >> 9, l = (p >> 3) & 63, j = p & 7;
        int ks = seg >> 3, nt = seg & 7;
        int k = ks * 32 + ((l >> 4) << 3) + j;
        int n = nt * 16 + (l & 15);
        W1P[p] = (k < GD) ? f2bf(W1[k * FD + n]) : (u16)0;
    }
    for (int p = g0; p < 32 * 512; p += gstep) {
        int seg = p >> 9, l = (p >> 3) & 63, j = p & 7;
        int half = seg >> 4, ks = (seg >> 3) & 1, nt = seg & 7;
        int k = half * 64 + ks * 32 + ((l >> 4) << 3) + j;
        int n = nt * 16 + (l & 15);
        int idx = k * FD + n;
        W2P[p]  = f2bf(W2[idx]);
        WiP[p]  = f2bf(Wi[idx]);
        Wo1P[p] = f2bf(Wo1[idx]);
        Wo2P[p] = f2bf(Wo2[idx]);
    }
}

// ---------------- k1: init = features @ W_init -> bf16 ----------------
// 500 blocks x 64 threads, 16 rows/block. No LDS, no barriers: A-frags are
// converted fp32->bf16 directly in registers; B-frags streamed from WiP (L2).
__global__ __launch_bounds__(64) void k1_init(const float* __restrict__ feat,
                                              const u16* __restrict__ WiP,
                                              u16* __restrict__ initB) {
    const int lane = threadIdx.x;
    const int quad = lane >> 4, col = lane & 15;
    const int row0 = blockIdx.x * 16;

    f32x4 acc[8];
    const f32x4 zf = {0.f, 0.f, 0.f, 0.f};
#pragma unroll
    for (int nt = 0; nt < 8; ++nt) acc[nt] = zf;

#pragma unroll
    for (int half = 0; half < 2; ++half)
#pragma unroll
        for (int ks = 0; ks < 2; ++ks) {
            const int ka = half * 64 + ks * 32 + quad * 8;
            const float* src = &feat[(size_t)(row0 + col) * FD + ka];
            float4 v0 = *(const float4*)src;
            float4 v1 = *(const float4*)(src + 4);
            short8 a;
            u32* ap = (u32*)&a;
            ap[0] = pkbf(v0.x, v0.y);
            ap[1] = pkbf(v0.z, v0.w);
            ap[2] = pkbf(v1.x, v1.y);
            ap[3] = pkbf(v1.z, v1.w);
#pragma unroll
            for (int nt = 0; nt < 8; ++nt) {
                short8 bfr = *(const short8*)&WiP[(((half * 2 + ks) * 8 + nt) << 9) + (lane << 3)];
                acc[nt] = mfma16(a, bfr, acc[nt]);
            }
        }
#pragma unroll
    for (int nt = 0; nt < 8; ++nt)
#pragma unroll
        for (int r = 0; r < 4; ++r)
            initB[(size_t)(row0 + quad * 4 + r) * FD + nt * 16 + col] = f2bf(acc[nt][r]);
}

// ---------------- k2: fused CFConv + attention, 2 atoms / block ----------------
// Per-wave LDS region (8704 B): rbf [32][68] overlaid by H [32][136]; waves are
// fully independent until the epilogue combine -> only 3 barriers per block.
// LDS total 34816 B -> 4 blocks/CU (16 waves, 50% occupancy cap).
// B-fragments streamed from packed global (L2-resident); epilogue gather stays
// at use site (round-0 pattern: no forced-live registers, no spill).
__global__ __launch_bounds__(256, 4) void k2_main(
    const float* __restrict__ rbf, const int* __restrict__ nl,
    const u16* __restrict__ initB,
    const u16* __restrict__ W1P, const u16* __restrict__ W2P,
    const float* __restrict__ b1, const float* __restrict__ b2,
    const float* __restrict__ nbrw,
    float* __restrict__ aggOut, float* __restrict__ attnO) {
    __shared__ alignas(16) char smem[34816];
    const int tid = threadIdx.x, wid = tid >> 6, lane = tid & 63;
    const int quad = lane >> 4, col = lane & 15, rw = wid * 32;
    const int blk = blockIdx.x;
    const int b = blk / 500;
    const int n0 = (blk - b * 500) * 2;
    const int atom0 = b * NA + n0;

    u16* wv = (u16*)smem + wid * 4352;       // per-wave region (4352 u16 = 8704 B)
    float* logitS = (float*)smem;            // [128]    bytes 0..511   (wave0 region, post-barrier)
    float* aggS   = (float*)(smem + 1024);   // [4][128] bytes 1024..3071

    // neighbor row offsets (8 ints/thread, quad-broadcast loads)
    int rowoff[2][4];
#pragma unroll
    for (int mt = 0; mt < 2; ++mt)
#pragma unroll
        for (int r = 0; r < 4; ++r)
            rowoff[mt][r] = (b * NA + nl[atom0 * MD + rw + mt * 16 + quad * 4 + r]) * FD;

    // ---- per-wave rbf staging: global rows rw..rw+31 -> wv [32][68] bf16 ----
    {
        const float* rsrc = rbf + (size_t)(atom0 * MD + rw) * GD;
        for (int i = lane; i < 800; i += 64) {
            int e = 2 * i;
            int r = e / 50, g = e - r * 50;
            float2 v = *(const float2*)&rsrc[e];
            *(u32*)&wv[r * 68 + g] = pkbf(v.x, v.y);
        }
        for (int i = lane; i < 448; i += 64) {  // zero K-pad cols [50,64)
            int r = i / 14;
            wv[r * 68 + 50 + (i - r * 14)] = 0;
        }
    }

    // ---- layer 1: rbf @ W1 (A from own-wave LDS, B from packed global) ----
    f32x4 acc[2][8];
    const f32x4 zf = {0.f, 0.f, 0.f, 0.f};
#pragma unroll
    for (int mt = 0; mt < 2; ++mt)
#pragma unroll
        for (int nt = 0; nt < 8; ++nt) acc[mt][nt] = zf;
#pragma unroll
    for (int ks = 0; ks < 2; ++ks) {
        const int ka = ks * 32 + quad * 8;
        short8 a0 = *(const short8*)&wv[col * 68 + ka];
        short8 a1 = *(const short8*)&wv[(16 + col) * 68 + ka];
#pragma unroll
        for (int nt = 0; nt < 8; ++nt) {
            short8 bfr = *(const short8*)&W1P[((ks * 8 + nt) << 9) + (lane << 3)];
            acc[0][nt] = mfma16(a0, bfr, acc[0][nt]);
            acc[1][nt] = mfma16(a1, bfr, acc[1][nt]);
        }
    }

    // ---- H = tanh(.+b1) -> own-wave region as [32][136] (clobbers own rbf only) ----
    float bias[8];
#pragma unroll
    for (int nt = 0; nt < 8; ++nt) bias[nt] = b1[nt * 16 + col];
#pragma unroll
    for (int mt = 0; mt < 2; ++mt)
#pragma unroll
        for (int nt = 0; nt < 8; ++nt)
#pragma unroll
            for (int r = 0; r < 4; ++r) {
                int row = mt * 16 + quad * 4 + r;  // local row
                wv[row * 136 + nt * 16 + col] =
                    f2bf(tanh_fast(acc[mt][nt][r] + bias[nt]));
            }

    // ---- layer 2: H @ W2 (A from own-wave LDS, B from packed global) ----
    f32x4 acc2[2][8];
#pragma unroll
    for (int mt = 0; mt < 2; ++mt)
#pragma unroll
        for (int nt = 0; nt < 8; ++nt) acc2[mt][nt] = zf;
#pragma unroll
    for (int half = 0; half < 2; ++half)
#pragma unroll
        for (int ks = 0; ks < 2; ++ks) {
            const int ka = half * 64 + ks * 32 + quad * 8;
            short8 a0 = *(const short8*)&wv[col * 136 + ka];
            short8 a1 = *(const short8*)&wv[(16 + col) * 136 + ka];
#pragma unroll
            for (int nt = 0; nt < 8; ++nt) {
                short8 bfr = *(const short8*)&W2P[(((half * 2 + ks) * 8 + nt) << 9) + (lane << 3)];
                acc2[0][nt] = mfma16(a0, bfr, acc2[0][nt]);
                acc2[1][nt] = mfma16(a1, bfr, acc2[1][nt]);
            }
        }

    // ---- epilogue: conv (gather at use site), logits, softmax, agg ----
    float wv8[8];
#pragma unroll
    for (int nt = 0; nt < 8; ++nt) {
        bias[nt] = b2[nt * 16 + col];
        wv8[nt] = nbrw[nt * 16 + col];
    }
    float part[2][4] = {{0.f, 0.f, 0.f, 0.f}, {0.f, 0.f, 0.f, 0.f}};
#pragma unroll
    for (int mt = 0; mt < 2; ++mt)
#pragma unroll
        for (int nt = 0; nt < 8; ++nt)
#pragma unroll
            for (int r = 0; r < 4; ++r) {
                float nb = bf2f(initB[rowoff[mt][r] + nt * 16 + col]);
                float cv = nb * (acc2[mt][nt][r] + bias[nt]);
                acc2[mt][nt][r] = cv;  // conv stays in regs (fp32)
                part[mt][r] += cv * wv8[nt];
            }
#pragma unroll
    for (int d = 1; d < 16; d <<= 1)
#pragma unroll
        for (int mt = 0; mt < 2; ++mt)
#pragma unroll
            for (int r = 0; r < 4; ++r)
                part[mt][r] += __shfl_xor(part[mt][r], d, 64);

    __syncthreads();  // barrier 1: all waves' H reads done before aux aliases wave0 region
    if (col == 0) {
#pragma unroll
        for (int mt = 0; mt < 2; ++mt)
#pragma unroll
            for (int r = 0; r < 4; ++r)
                logitS[rw + mt * 16 + quad * 4 + r] = part[mt][r];
    }
    __syncthreads();  // barrier 2: logits visible

    // all-wave redundant softmax: each wave owns its atom's 64 logits
    float attw[2][4];
    {
        const int base = rw & 64;  // waves 0,1 -> atom0 ; waves 2,3 -> atom1
        float x = logitS[base + lane];
        float m = x;
#pragma unroll
        for (int d = 1; d < 64; d <<= 1) m = fmaxf(m, __shfl_xor(m, d, 64));
        float e = __expf(x - m);
        float s = e;
#pragma unroll
        for (int d = 1; d < 64; d <<= 1) s += __shfl_xor(s, d, 64);
        float a = e / s;
        if ((wid & 1) == 0)
            attnO[(size_t)(atom0 + (wid >> 1)) * MD + lane] = a;
        // redistribute to row owners: row R's attn sits at lane R-base
#pragma unroll
        for (int mt = 0; mt < 2; ++mt)
#pragma unroll
            for (int r = 0; r < 4; ++r)
                attw[mt][r] = __shfl(a, (rw & 32) + mt * 16 + quad * 4 + r, 64);
    }

    float aggp[8] = {0.f, 0.f, 0.f, 0.f, 0.f, 0.f, 0.f, 0.f};
#pragma unroll
    for (int mt = 0; mt < 2; ++mt)
#pragma unroll
        for (int r = 0; r < 4; ++r) {
            float a = attw[mt][r];
#pragma unroll
            for (int nt = 0; nt < 8; ++nt) aggp[nt] += a * acc2[mt][nt][r];
        }
#pragma unroll
    for (int d = 16; d < 64; d <<= 1)
#pragma unroll
        for (int nt = 0; nt < 8; ++nt) aggp[nt] += __shfl_xor(aggp[nt], d, 64);
    if (quad == 0) {
#pragma unroll
        for (int nt = 0; nt < 8; ++nt) aggS[wid * 128 + nt * 16 + col] = aggp[nt];
    }
    __syncthreads();  // barrier 3: partials visible
    {
        int a = tid >> 7;   // which atom
        int c = tid & 127;  // feature
        float v = aggS[(2 * a) * 128 + c] + aggS[(2 * a + 1) * 128 + c];
        aggOut[(size_t)(atom0 + a) * FD + c] = v;  // agg scratch in d_out rows
    }
}

// ---------------- k3: out = tanh(agg@Wo1+bo1)@Wo2+bo2, IN PLACE on d_out rows ----------------
// 500 blocks x 64 threads, 16 rows/block. LDS [16][136] only for the t1
// transpose; single (1-wave, cheap) barrier.
__global__ __launch_bounds__(64) void k3_out(
    float* __restrict__ outp, const u16* __restrict__ Wo1P,
    const u16* __restrict__ Wo2P, const float* __restrict__ bo1,
    const float* __restrict__ bo2) {
    __shared__ alignas(16) u16 sT[16 * 136];
    const int lane = threadIdx.x;
    const int quad = lane >> 4, col = lane & 15;
    const int row0 = blockIdx.x * 16;

    f32x4 acc[8];
    const f32x4 zf = {0.f, 0.f, 0.f, 0.f};
#pragma unroll
    for (int nt = 0; nt < 8; ++nt) acc[nt] = zf;
#pragma unroll
    for (int half = 0; half < 2; ++half)
#pragma unroll
        for (int ks = 0; ks < 2; ++ks) {
            const int ka = half * 64 + ks * 32 + quad * 8;
            const float* src = &outp[(size_t)(row0 + col) * FD + ka];
            float4 v0 = *(const float4*)src;
            float4 v1 = *(const float4*)(src + 4);
            short8 a;
            u32* ap = (u32*)&a;
            ap[0] = pkbf(v0.x, v0.y);
            ap[1] = pkbf(v0.z, v0.w);
            ap[2] = pkbf(v1.x, v1.y);
            ap[3] = pkbf(v1.z, v1.w);
#pragma unroll
            for (int nt = 0; nt < 8; ++nt) {
                short8 bfr = *(const short8*)&Wo1P[(((half * 2 + ks) * 8 + nt) << 9) + (lane << 3)];
                acc[nt] = mfma16(a, bfr, acc[nt]);
            }
        }

#pragma unroll
    for (int nt = 0; nt < 8; ++nt) {
        float bias = bo1[nt * 16 + col];
#pragma unroll
        for (int r = 0; r < 4; ++r)
            sT[(quad * 4 + r) * 136 + nt * 16 + col] =
                f2bf(tanh_fast(acc[nt][r] + bias));
    }
    __syncthreads();  // single-wave block: cheap; guarantees t1 write->read order

    f32x4 acc2[8];
#pragma unroll
    for (int nt = 0; nt < 8; ++nt) acc2[nt] = zf;
#pragma unroll
    for (int half = 0; half < 2; ++half)
#pragma unroll
        for (int ks = 0; ks < 2; ++ks) {
            const int ka = half * 64 + ks * 32 + quad * 8;
            short8 a0 = *(const short8*)&sT[col * 136 + ka];
#pragma unroll
            for (int nt = 0; nt < 8; ++nt) {
                short8 bfr = *(const short8*)&Wo2P[(((half * 2 + ks) * 8 + nt) << 9) + (lane << 3)];
                acc2[nt] = mfma16(a0, bfr, acc2[nt]);
            }
        }
#pragma unroll
    for (int nt = 0; nt < 8; ++nt) {
        float bias = bo2[nt * 16 + col];
#pragma unroll
        for (int r = 0; r < 4; ++r)
            outp[(size_t)(row0 + quad * 4 + r) * FD + nt * 16 + col] =
                acc2[nt][r] + bias;
    }
}

extern "C" void kernel_launch(void* const* d_in, const int* in_sizes, int n_in,
                              void* d_out, int out_size, void* d_ws,
                              size_t ws_size, hipStream_t stream) {
    const float* feat = (const float*)d_in[0];
    const float* rbf  = (const float*)d_in[1];
    const int*   nl   = (const int*)d_in[2];
    const float* Wi   = (const float*)d_in[3];
    const float* W1   = (const float*)d_in[4];
    const float* b1   = (const float*)d_in[5];
    const float* W2   = (const float*)d_in[6];
    const float* b2   = (const float*)d_in[7];
    const float* nbrw = (const float*)d_in[8];
    const float* Wo1  = (const float*)d_in[9];
    const float* bo1  = (const float*)d_in[10];
    const float* Wo2  = (const float*)d_in[11];
    const float* bo2  = (const float*)d_in[12];

    float* outp  = (float*)d_out;               // [8000][128] (agg scratch, then final)
    float* attnp = outp + (size_t)TOTAL * FD;   // [8000][64]

    char* ws = (char*)d_ws;                     // total use: 2,195,456 B
    u16* initB = (u16*)ws;                      // 2,048,000 B
    u16* W1P   = (u16*)(ws + 2048000);          // 16,384 B
    u16* W2P   = (u16*)(ws + 2064384);          // 32,768 B
    u16* WiP   = (u16*)(ws + 2097152);          // 32,768 B
    u16* Wo1P  = (u16*)(ws + 2129920);          // 32,768 B
    u16* Wo2P  = (u16*)(ws + 2162688);          // 32,768 B

    hipLaunchKernelGGL(k0_prep, dim3(40), dim3(256), 0, stream,
                       W1, W2, Wi, Wo1, Wo2, W1P, W2P, WiP, Wo1P, Wo2P);
    hipLaunchKernelGGL(k1_init, dim3(500), dim3(64), 0, stream, feat, WiP, initB);
    hipLaunchKernelGGL(k2_main, dim3(4000), dim3(256), 0, stream,
                       rbf, nl, initB, W1P, W2P, b1, b2, nbrw, outp, attnp);
    hipLaunchKernelGGL(k3_out, dim3(500), dim3(64), 0, stream,
                       outp, Wo1P, Wo2P, bo1, bo2);
}